// Round 2
// baseline (137.976 us; speedup 1.0000x reference)
//
#include <hip/hip_runtime.h>
#include <hip/hip_bf16.h>

typedef __bf16 bf16x8 __attribute__((ext_vector_type(8)));
typedef float floatx4 __attribute__((ext_vector_type(4)));

constexpr int SEQ = 4096;
constexpr int NH  = 8;
constexpr int DH  = 128;
constexpr int BLK = 64;
constexpr int QBLOCKS = SEQ / BLK;          // 64
constexpr int ROWSTRIDE = NH * DH;          // 1024 elements per token row
constexpr float SCALE = 0.088388347648318447f;  // 1/sqrt(128)

// ---- runtime dtype probe -----------------------------------------------
// For a packed-bf16 buffer, bits 14..7 of each u32 word are the LOW half's
// exponent field -> concentrated in [96,134] for standard-normal data.
// For an fp32 buffer, bits 14..7 are mid-mantissa bits -> uniform 0..255
// (~15% in range). 128-word vote separates the two cases decisively.
__device__ __forceinline__ bool buf_is_bf16(const unsigned* w) {
    int cnt = 0;
#pragma unroll 1
    for (int i = 0; i < 128; ++i) {
        unsigned e = (w[i] >> 7) & 0xFFu;
        cnt += (e >= 96u && e <= 134u) ? 1 : 0;
    }
    return cnt >= 96;
}

template<bool IS_BF16> struct IO;
template<> struct IO<true> {
    using T = __bf16;
    static __device__ __forceinline__ bf16x8 load8(const T* p) {
        return *(const bf16x8*)p;
    }
};
template<> struct IO<false> {
    using T = float;
    static __device__ __forceinline__ bf16x8 load8(const T* p) {
        float4 a = *(const float4*)p;
        float4 b = *(const float4*)(p + 4);
        bf16x8 r = { (__bf16)a.x, (__bf16)a.y, (__bf16)a.z, (__bf16)a.w,
                     (__bf16)b.x, (__bf16)b.y, (__bf16)b.z, (__bf16)b.w };
        return r;
    }
};

// Block-sparse flash attention.
// Visible k-blocks for q-block i (PATTERN_ID=0): {0,1,i-1,i} ∩ [0,i].
// Mask is block-granular: no intra-block masking needed.
template<bool IS_BF16>
__global__ __launch_bounds__(256) void sparse_attn_kernel(
    const void* __restrict__ Qv,
    const void* __restrict__ Kv,
    const void* __restrict__ Vv,
    void* __restrict__ Outv)
{
    // self-gate on detected dtype; the mismatched instantiation exits.
    if (buf_is_bf16((const unsigned*)Qv) != IS_BF16) return;

    using T = typename IO<IS_BF16>::T;
    const T* Q = (const T*)Qv;
    const T* K = (const T*)Kv;
    const T* V = (const T*)Vv;
    T* Out = (T*)Outv;

    const int qb   = blockIdx.x;        // q-block 0..63
    const int h    = blockIdx.y;        // head 0..7
    const int wave = threadIdx.x >> 6;  // 0..3, each wave = 16-query strip
    const int lane = threadIdx.x & 63;
    const int quad = lane >> 4;         // 0..3
    const int l16  = lane & 15;

    // P strip per wave: 16 rows x 64 cols bf16, +8 pad to break bank conflicts
    __shared__ __align__(16) __bf16 p_lds[4][16][BLK + 8];

    // ---- Q strip A-fragments: rows m = l16, k-chunks of 32 (quad*8+j) ----
    const int qrow = qb * BLK + wave * 16 + l16;
    const T* qptr = Q + (size_t)qrow * ROWSTRIDE + h * DH;
    bf16x8 qfrag[4];
#pragma unroll
    for (int s = 0; s < 4; ++s)
        qfrag[s] = IO<IS_BF16>::load8(qptr + s * 32 + quad * 8);

    // ---- accumulators ----
    floatx4 o_acc[8];
#pragma unroll
    for (int n = 0; n < 8; ++n) o_acc[n] = floatx4{0.f, 0.f, 0.f, 0.f};
    float m_run[4], l_run[4];
#pragma unroll
    for (int r = 0; r < 4; ++r) { m_run[r] = -1e30f; l_run[r] = 0.f; }

    // ---- visible k-block list (unique, ascending) ----
    int blist[4];
    int nb = 0;
    {
        int cand[4] = {0, 1, qb - 1, qb};
        for (int i = 0; i < 4; ++i) {
            int b = cand[i];
            if (b < 0 || b > qb) continue;
            bool dup = false;
            for (int j = 0; j < nb; ++j) dup = dup || (blist[j] == b);
            if (!dup) blist[nb++] = b;
        }
    }

    for (int bi = 0; bi < nb; ++bi) {
        const int kb = blist[bi];

        // ---- S = Q K^T  (16 x 64, 4 n-tiles) ----
        floatx4 sfrag[4];
#pragma unroll
        for (int n = 0; n < 4; ++n) {
            floatx4 c = floatx4{0.f, 0.f, 0.f, 0.f};
            const T* kptr =
                K + (size_t)(kb * BLK + n * 16 + l16) * ROWSTRIDE + h * DH;
#pragma unroll
            for (int s = 0; s < 4; ++s) {
                bf16x8 kf = IO<IS_BF16>::load8(kptr + s * 32 + quad * 8);
                c = __builtin_amdgcn_mfma_f32_16x16x32_bf16(qfrag[s], kf, c, 0, 0, 0);
            }
            sfrag[n] = c;
        }

        // ---- online softmax: row stats per reg r (row = quad*4+r),
        //      replicated across the 16 lanes of each quad group ----
        float mnew[4];
#pragma unroll
        for (int r = 0; r < 4; ++r) {
            float mx = m_run[r];
#pragma unroll
            for (int n = 0; n < 4; ++n) {
                sfrag[n][r] *= SCALE;
                mx = fmaxf(mx, sfrag[n][r]);
            }
#pragma unroll
            for (int off = 1; off < 16; off <<= 1)
                mx = fmaxf(mx, __shfl_xor(mx, off, 64));
            mnew[r] = mx;
        }
#pragma unroll
        for (int r = 0; r < 4; ++r) {
            float alpha = __expf(m_run[r] - mnew[r]);
            float rs = 0.f;
#pragma unroll
            for (int n = 0; n < 4; ++n) {
                float p = __expf(sfrag[n][r] - mnew[r]);
                sfrag[n][r] = p;
                rs += p;
            }
#pragma unroll
            for (int off = 1; off < 16; off <<= 1)
                rs += __shfl_xor(rs, off, 64);
            l_run[r] = l_run[r] * alpha + rs;
            m_run[r] = mnew[r];
#pragma unroll
            for (int n = 0; n < 8; ++n) o_acc[n][r] *= alpha;
        }

        // ---- P: C-layout regs -> LDS -> A-layout frags ----
#pragma unroll
        for (int n = 0; n < 4; ++n)
#pragma unroll
            for (int r = 0; r < 4; ++r)
                p_lds[wave][quad * 4 + r][n * 16 + l16] = (__bf16)sfrag[n][r];
        __syncthreads();

        // ---- O += P V  (contraction over 64 keys, 2 chunks of 32) ----
#pragma unroll
        for (int s2 = 0; s2 < 2; ++s2) {
            bf16x8 pa = *(const bf16x8*)&p_lds[wave][l16][s2 * 32 + quad * 8];
            const T* vptr =
                V + (size_t)(kb * BLK + s2 * 32 + quad * 8) * ROWSTRIDE + h * DH + l16;
#pragma unroll
            for (int n = 0; n < 8; ++n) {
                bf16x8 vb;
#pragma unroll
                for (int j = 0; j < 8; ++j)
                    vb[j] = (__bf16)vptr[(size_t)j * ROWSTRIDE + n * 16];
                o_acc[n] = __builtin_amdgcn_mfma_f32_16x16x32_bf16(pa, vb, o_acc[n], 0, 0, 0);
            }
        }
        __syncthreads();
    }

    // ---- epilogue: normalize and store (row = quad*4+r, col = n*16+l16) ----
    const int orow_base = qb * BLK + wave * 16 + quad * 4;
#pragma unroll
    for (int r = 0; r < 4; ++r) {
        float inv = 1.f / l_run[r];
        T* optr = Out + (size_t)(orow_base + r) * ROWSTRIDE + h * DH + l16;
#pragma unroll
        for (int n = 0; n < 8; ++n)
            optr[n * 16] = (T)(o_acc[n][r] * inv);
    }
}

extern "C" void kernel_launch(void* const* d_in, const int* in_sizes, int n_in,
                              void* d_out, int out_size, void* d_ws, size_t ws_size,
                              hipStream_t stream) {
    const void* Q = d_in[0];
    const void* K = d_in[1];
    const void* V = d_in[2];
    // d_in[3] (block_mask) is deterministic from PATTERN_ID=0 constants; hardcoded in-kernel.

    dim3 grid(QBLOCKS, NH);
    dim3 block(256);
    // Launch both dtype instantiations; each self-gates on a deterministic
    // probe of Q's bit patterns, so exactly one does the work. Graph-safe.
    sparse_attn_kernel<true ><<<grid, block, 0, stream>>>(Q, K, V, d_out);
    sparse_attn_kernel<false><<<grid, block, 0, stream>>>(Q, K, V, d_out);
}

// Round 3
// 125.913 us; speedup vs baseline: 1.0958x; 1.0958x over previous
//
#include <hip/hip_runtime.h>
#include <hip/hip_bf16.h>

typedef __bf16 bf16x8 __attribute__((ext_vector_type(8)));
typedef float floatx4 __attribute__((ext_vector_type(4)));

constexpr int SEQ = 4096;
constexpr int NH  = 8;
constexpr int DH  = 128;
constexpr int BLK = 64;
constexpr int QBLOCKS = SEQ / BLK;   // 64
constexpr int RS = NH * DH;          // 1024 floats per token row
constexpr float SCALE = 0.088388347648318447f;  // 1/sqrt(128)

// fp32 global -> bf16x8 fragment (inputs are fp32; MFMA computes in bf16)
__device__ __forceinline__ bf16x8 load8f(const float* p) {
    float4 a = *(const float4*)p;
    float4 b = *(const float4*)(p + 4);
    bf16x8 r = { (__bf16)a.x, (__bf16)a.y, (__bf16)a.z, (__bf16)a.w,
                 (__bf16)b.x, (__bf16)b.y, (__bf16)b.z, (__bf16)b.w };
    return r;
}

// Cooperative V-tile staging into fragment-major LDS.
// v_lds layout: [s2][nt][lane][j] bf16; the PV B-frag for mfma (s2, nt) is
// 16 contiguous bytes per lane -> one ds_read_b128 (m134 measured-good case).
// Thread t: col n_t = t&127, k-half kh = t>>7; loads 8-k column segments
// (coalesced 256B/instr across the wave), packs one ds_write_b128 per group.
__device__ __forceinline__ void stage_v(const float* __restrict__ V,
                                        int kb, int h, int n_t, int kh,
                                        __bf16* __restrict__ dst) {
    const float* base = V + (size_t)(kb * BLK + kh * 32) * RS + h * DH + n_t;
    const int nt = n_t >> 4;
    const int lbase = n_t & 15;
#pragma unroll
    for (int g = 0; g < 4; ++g) {
        bf16x8 pk;
#pragma unroll
        for (int j = 0; j < 8; ++j)
            pk[j] = (__bf16)base[(size_t)(g * 8 + j) * RS];
        __bf16* d = dst + ((size_t)((kh * 8 + nt) * 64 + lbase + 16 * g)) * 8;
        *(bf16x8*)d = pk;
    }
}

// Block-sparse flash attention, PATTERN_ID=0.
// Visible k-blocks for q-block i: {0,1,i-1,i} ∩ [0,i]; block-granular mask.
__global__ __launch_bounds__(256) void sparse_attn_kernel(
    const float* __restrict__ Q,
    const float* __restrict__ K,
    const float* __restrict__ V,
    float* __restrict__ Out)
{
    const int qb   = blockIdx.x;        // q-block 0..63
    const int h    = blockIdx.y;        // head 0..7
    const int tid  = threadIdx.x;
    const int wave = tid >> 6;          // 0..3, each wave = 16-query strip
    const int lane = tid & 63;
    const int quad = lane >> 4;
    const int l16  = lane & 15;

    // double-buffered V tile in frag-major order + per-wave P strips
    __shared__ __align__(16) __bf16 v_lds[2][2][8][64][8];   // 32 KB
    __shared__ __align__(16) __bf16 p_lds[4][16][BLK + 8];   // 9.2 KB

    const int n_t = tid & 127;  // staging col
    const int kh  = tid >> 7;   // staging k-half

    // ---- Q strip A-fragments: rows m = l16, k-chunks of 32 (quad*8+j) ----
    const int qrow = qb * BLK + wave * 16 + l16;
    const float* qp = Q + (size_t)qrow * RS + h * DH;
    bf16x8 qfrag[4];
#pragma unroll
    for (int s = 0; s < 4; ++s)
        qfrag[s] = load8f(qp + s * 32 + quad * 8);

    // ---- accumulators ----
    floatx4 o_acc[8];
#pragma unroll
    for (int n = 0; n < 8; ++n) o_acc[n] = floatx4{0.f, 0.f, 0.f, 0.f};
    float m_run[4], l_run[4];
#pragma unroll
    for (int r = 0; r < 4; ++r) { m_run[r] = -1e30f; l_run[r] = 0.f; }

    // ---- visible k-block list (unique, ascending) ----
    int blist[4];
    int nb = 0;
    {
        int cand[4] = {0, 1, qb - 1, qb};
        for (int i = 0; i < 4; ++i) {
            int b = cand[i];
            if (b < 0 || b > qb) continue;
            bool dup = false;
            for (int j = 0; j < nb; ++j) dup = dup || (blist[j] == b);
            if (!dup) blist[nb++] = b;
        }
    }

    // prologue: stage first V tile into buffer 0
    stage_v(V, blist[0], h, n_t, kh, &v_lds[0][0][0][0][0]);

    for (int bi = 0; bi < nb; ++bi) {
        __syncthreads();  // v_lds[bi&1] staged; prev compute (bi-1) done
        // prefetch-stage next V tile into the other buffer (overlaps compute)
        if (bi + 1 < nb)
            stage_v(V, blist[bi + 1], h, n_t, kh,
                    &v_lds[(bi + 1) & 1][0][0][0][0]);

        const int kb  = blist[bi];
        const int buf = bi & 1;

        // ---- S = Q K^T  (16 x 64, 4 n-tiles); K frags direct from global
        //      (contiguous 16B along dh per lane) ----
        floatx4 sfrag[4];
#pragma unroll
        for (int n = 0; n < 4; ++n) {
            floatx4 c = floatx4{0.f, 0.f, 0.f, 0.f};
            const float* kp =
                K + (size_t)(kb * BLK + n * 16 + l16) * RS + h * DH;
#pragma unroll
            for (int s = 0; s < 4; ++s) {
                bf16x8 kf = load8f(kp + s * 32 + quad * 8);
                c = __builtin_amdgcn_mfma_f32_16x16x32_bf16(qfrag[s], kf, c, 0, 0, 0);
            }
            sfrag[n] = c;
        }

        // ---- online softmax; row stats per reg r (row = quad*4+r),
        //      replicated across the 16 lanes of each quad group ----
        float mnew[4];
#pragma unroll
        for (int r = 0; r < 4; ++r) {
            float mx = m_run[r];
#pragma unroll
            for (int n = 0; n < 4; ++n) {
                sfrag[n][r] *= SCALE;
                mx = fmaxf(mx, sfrag[n][r]);
            }
#pragma unroll
            for (int off = 1; off < 16; off <<= 1)
                mx = fmaxf(mx, __shfl_xor(mx, off, 64));
            mnew[r] = mx;
        }
#pragma unroll
        for (int r = 0; r < 4; ++r) {
            float alpha = __expf(m_run[r] - mnew[r]);
            float rs = 0.f;
#pragma unroll
            for (int n = 0; n < 4; ++n) {
                float p = __expf(sfrag[n][r] - mnew[r]);
                sfrag[n][r] = p;
                rs += p;
            }
#pragma unroll
            for (int off = 1; off < 16; off <<= 1)
                rs += __shfl_xor(rs, off, 64);
            l_run[r] = l_run[r] * alpha + rs;
            m_run[r] = mnew[r];
#pragma unroll
            for (int n = 0; n < 8; ++n) o_acc[n][r] *= alpha;
        }

        // ---- P: C-layout regs -> per-wave LDS -> A-layout frags
        //      (no barrier: p_lds[wave] is wave-private) ----
#pragma unroll
        for (int n = 0; n < 4; ++n)
#pragma unroll
            for (int r = 0; r < 4; ++r)
                p_lds[wave][quad * 4 + r][n * 16 + l16] = (__bf16)sfrag[n][r];

        // ---- O += P V : B-frags are single contiguous b128 reads ----
#pragma unroll
        for (int s2 = 0; s2 < 2; ++s2) {
            bf16x8 pa = *(const bf16x8*)&p_lds[wave][l16][s2 * 32 + quad * 8];
#pragma unroll
            for (int n = 0; n < 8; ++n) {
                bf16x8 vb = *(const bf16x8*)&v_lds[buf][s2][n][lane][0];
                o_acc[n] = __builtin_amdgcn_mfma_f32_16x16x32_bf16(pa, vb, o_acc[n], 0, 0, 0);
            }
        }
    }

    // ---- epilogue: normalize and store (row = quad*4+r, col = n*16+l16) ----
    const int orow_base = qb * BLK + wave * 16 + quad * 4;
#pragma unroll
    for (int r = 0; r < 4; ++r) {
        float inv = 1.f / l_run[r];
        float* op = Out + (size_t)(orow_base + r) * RS + h * DH + l16;
#pragma unroll
        for (int n = 0; n < 8; ++n)
            op[n * 16] = o_acc[n][r] * inv;
    }
}

extern "C" void kernel_launch(void* const* d_in, const int* in_sizes, int n_in,
                              void* d_out, int out_size, void* d_ws, size_t ws_size,
                              hipStream_t stream) {
    const float* Q = (const float*)d_in[0];
    const float* K = (const float*)d_in[1];
    const float* V = (const float*)d_in[2];
    // d_in[3] (block_mask) is deterministic from PATTERN_ID=0; hardcoded.
    float* Out = (float*)d_out;

    dim3 grid(QBLOCKS, NH);
    dim3 block(256);
    sparse_attn_kernel<<<grid, block, 0, stream>>>(Q, K, V, Out);
}